// Round 6
// baseline (335.536 us; speedup 1.0000x reference)
//
#include <hip/hip_runtime.h>

#define N_NODES 50000
#define N_EDGES 800000
#define DIM 128
#define NHB 16                          // histogram/fill blocks
#define EPB (N_EDGES / NHB)             // 50000 edges per block
#define NPACK (N_NODES / 2)             // 25000 packed dwords (2x u16 per dword)
#define SCAN_ELEMS 1024
#define SCAN_BLOCKS ((N_NODES + SCAN_ELEMS - 1) / SCAN_ELEMS)  // 49

typedef unsigned int uint;

__device__ __forceinline__ uint bf16pair(float a, float b) {
  uint ua = __float_as_uint(a); ua = (ua + 0x7FFFu + ((ua >> 16) & 1u)) >> 16;
  uint ub = __float_as_uint(b); ub = (ub + 0x7FFFu + ((ub >> 16) & 1u)) >> 16;
  return ua | (ub << 16);
}

// ---------------- per-block histograms of dst and src (LDS atomics, plain-store flush) ----------------
__global__ __launch_bounds__(1024) void hist_kernel(
    const int* __restrict__ src, const int* __restrict__ dst,
    uint* __restrict__ hist_src, uint* __restrict__ hist_dst) {
  extern __shared__ uint h[];   // NPACK dwords = 100 KB
  int b = blockIdx.x, t = threadIdx.x;
  int e0 = b * EPB;

  // dst pass
  for (int i = t; i < NPACK; i += 1024) h[i] = 0;
  __syncthreads();
  for (int i = t; i < EPB; i += 1024) {
    int d = dst[e0 + i];
    atomicAdd(&h[d >> 1], 1u << ((d & 1) << 4));
  }
  __syncthreads();
  for (int i = t; i < NPACK; i += 1024) hist_dst[b * NPACK + i] = h[i];
  __syncthreads();

  // src pass
  for (int i = t; i < NPACK; i += 1024) h[i] = 0;
  __syncthreads();
  for (int i = t; i < EPB; i += 1024) {
    int s = src[e0 + i];
    atomicAdd(&h[s >> 1], 1u << ((s & 1) << 4));
  }
  __syncthreads();
  for (int i = t; i < NPACK; i += 1024) hist_src[b * NPACK + i] = h[i];
}

// ---------------- per-node cross-block prefix, totals, norms ----------------
__global__ __launch_bounds__(256) void prefix_kernel(
    const uint* __restrict__ hist_src, const uint* __restrict__ hist_dst,
    uint* __restrict__ P, int* __restrict__ cnt_in,
    float* __restrict__ norm_in, float* __restrict__ norm_out) {
  int i = blockIdx.x * 256 + threadIdx.x;   // packed dword index: nodes 2i, 2i+1
  if (i >= NPACK) return;
  uint r0 = 0, r1 = 0;
#pragma unroll
  for (int b = 0; b < NHB; ++b) {
    uint v = hist_dst[b * NPACK + i];
    P[b * N_NODES + 2 * i]     = r0;
    P[b * N_NODES + 2 * i + 1] = r1;
    r0 += v & 0xFFFFu; r1 += v >> 16;
  }
  cnt_in[2 * i] = (int)r0; cnt_in[2 * i + 1] = (int)r1;
  norm_in[2 * i]     = rsqrtf(fmaxf((float)r0, 1.0f));
  norm_in[2 * i + 1] = rsqrtf(fmaxf((float)r1, 1.0f));
  uint s0 = 0, s1 = 0;
#pragma unroll
  for (int b = 0; b < NHB; ++b) {
    uint v = hist_src[b * NPACK + i];
    s0 += v & 0xFFFFu; s1 += v >> 16;
  }
  norm_out[2 * i]     = rsqrtf(fmaxf((float)s0, 1.0f));
  norm_out[2 * i + 1] = rsqrtf(fmaxf((float)s1, 1.0f));
}

// ---------------- scan pass 1: per-block exclusive scan of cnt_in ----------------
__global__ __launch_bounds__(256) void scan1_kernel(
    const int* __restrict__ counts, int* __restrict__ partial,
    int* __restrict__ blockSums, int n) {
  __shared__ int wsum[4];
  int t = threadIdx.x;
  int base = blockIdx.x * SCAN_ELEMS + t * 4;
  int c[4];
#pragma unroll
  for (int i = 0; i < 4; ++i) c[i] = (base + i < n) ? counts[base + i] : 0;
  int s = c[0] + c[1] + c[2] + c[3];
  int lane = t & 63, wid = t >> 6;
  int v = s;
#pragma unroll
  for (int off = 1; off < 64; off <<= 1) {
    int u = __shfl_up(v, off);
    if (lane >= off) v += u;
  }
  if (lane == 63) wsum[wid] = v;
  __syncthreads();
  if (t == 0) {
    int run = 0;
#pragma unroll
    for (int i = 0; i < 4; ++i) { int tmp = wsum[i]; wsum[i] = run; run += tmp; }
    blockSums[blockIdx.x] = run;
  }
  __syncthreads();
  int excl = wsum[wid] + v - s;
  int o0 = excl;
  int o1 = o0 + c[0];
  int o2 = o1 + c[1];
  int o3 = o2 + c[2];
  if (base + 0 < n) partial[base + 0] = o0;
  if (base + 1 < n) partial[base + 1] = o1;
  if (base + 2 < n) partial[base + 2] = o2;
  if (base + 3 < n) partial[base + 3] = o3;
}

// ---------------- scan pass 2: serial scan of 49 block sums ----------------
__global__ void scan2_kernel(int* __restrict__ blockSums, int nb) {
  if (threadIdx.x == 0 && blockIdx.x == 0) {
    int run = 0;
    for (int i = 0; i < nb; ++i) { int t = blockSums[i]; blockSums[i] = run; run += t; }
  }
}

// ---------------- scan pass 3: offsets ----------------
__global__ __launch_bounds__(256) void scan3_kernel(
    const int* __restrict__ partial, const int* __restrict__ blockSums,
    int* __restrict__ offsets, int n, int E) {
  int t = threadIdx.x;
  int bo = blockSums[blockIdx.x];
  int base = blockIdx.x * SCAN_ELEMS + t * 4;
#pragma unroll
  for (int i = 0; i < 4; ++i) {
    int idx = base + i;
    if (idx < n) offsets[idx] = partial[idx] + bo;
  }
  if (blockIdx.x == 0 && t == 0) offsets[n] = E;
}

// ---------------- bucket fill via LDS cursor (no global atomics) ----------------
__global__ __launch_bounds__(1024) void fill_kernel(
    const int* __restrict__ src, const int* __restrict__ dst,
    const int* __restrict__ offsets, const uint* __restrict__ P,
    int* __restrict__ csr_src) {
  extern __shared__ uint cur[];  // NPACK dwords = 100 KB
  int b = blockIdx.x, t = threadIdx.x;
  for (int i = t; i < NPACK; i += 1024) cur[i] = 0;
  __syncthreads();
  int e0 = b * EPB;
  const uint* Pb = P + b * N_NODES;
  for (int i = t; i < EPB; i += 1024) {
    int d = dst[e0 + i];
    int s = src[e0 + i];
    uint sh = (uint)(d & 1) << 4;
    uint old = atomicAdd(&cur[d >> 1], 1u << sh);
    uint lpos = (old >> sh) & 0xFFFFu;
    csr_src[offsets[d] + (int)Pb[d] + (int)lpos] = s;
  }
}

// ---------------- y_bf16[r] = norm_out[r] * (x[r] @ W) ----------------
// 64 rows/block; W (64KB) in LDS, A direct from global (half-wave broadcast).
__global__ __launch_bounds__(256) void gemm_kernel(
    const float4* __restrict__ x4, const float4* __restrict__ W4,
    const float* __restrict__ norm_out, uint2* __restrict__ yb2, int n) {
  __shared__ float4 Wl4[DIM * 32];  // Wl4[k*32 + c4], 64KB
  int t = threadIdx.x;
#pragma unroll
  for (int i = 0; i < 16; ++i) Wl4[t + 256 * i] = W4[t + 256 * i];
  __syncthreads();

  int col4 = t & 31;
  int rg = t >> 5;
  int row0 = blockIdx.x * 64 + rg * 8;

  float4 acc[8];
#pragma unroll
  for (int i = 0; i < 8; ++i) acc[i] = make_float4(0.f, 0.f, 0.f, 0.f);

#pragma unroll 2
  for (int kc = 0; kc < 32; ++kc) {
    float4 w0 = Wl4[(4 * kc + 0) * 32 + col4];
    float4 w1 = Wl4[(4 * kc + 1) * 32 + col4];
    float4 w2 = Wl4[(4 * kc + 2) * 32 + col4];
    float4 w3 = Wl4[(4 * kc + 3) * 32 + col4];
#pragma unroll
    for (int i = 0; i < 8; ++i) {
      int gr = row0 + i;
      int cr = gr < n ? gr : n - 1;
      float4 a = x4[(size_t)cr * 32 + kc];
      acc[i].x = fmaf(a.x, w0.x, fmaf(a.y, w1.x, fmaf(a.z, w2.x, fmaf(a.w, w3.x, acc[i].x))));
      acc[i].y = fmaf(a.x, w0.y, fmaf(a.y, w1.y, fmaf(a.z, w2.y, fmaf(a.w, w3.y, acc[i].y))));
      acc[i].z = fmaf(a.x, w0.z, fmaf(a.y, w1.z, fmaf(a.z, w2.z, fmaf(a.w, w3.z, acc[i].z))));
      acc[i].w = fmaf(a.x, w0.w, fmaf(a.y, w1.w, fmaf(a.z, w2.w, fmaf(a.w, w3.w, acc[i].w))));
    }
  }

#pragma unroll
  for (int i = 0; i < 8; ++i) {
    int gr = row0 + i;
    if (gr < n) {
      float ns = norm_out[gr];
      float4 o = acc[i];
      uint2 packed;
      packed.x = bf16pair(o.x * ns, o.y * ns);
      packed.y = bf16pair(o.z * ns, o.w * ns);
      yb2[(size_t)gr * 32 + col4] = packed;
    }
  }
}

// ---------------- out[d] = relu(norm_in[d] * sum_seg ybf16[src] + b) ----------------
__global__ __launch_bounds__(256) void aggregate_kernel(
    const uint* __restrict__ yb, const int* __restrict__ csr_src,
    const int* __restrict__ offsets, const float* __restrict__ norm_in,
    const float2* __restrict__ b2, float2* __restrict__ out2, int n) {
  int t = threadIdx.x;
  int node = blockIdx.x * 4 + (t >> 6);
  if (node >= n) return;
  int lane = t & 63;
  int beg = offsets[node], end = offsets[node + 1];

  float ax0 = 0.f, ay0 = 0.f, ax1 = 0.f, ay1 = 0.f;
  float ax2 = 0.f, ay2 = 0.f, ax3 = 0.f, ay3 = 0.f;
  int j = beg;
  for (; j + 4 <= end; j += 4) {
    int s0 = csr_src[j + 0];
    int s1 = csr_src[j + 1];
    int s2 = csr_src[j + 2];
    int s3 = csr_src[j + 3];
    uint u0 = yb[(size_t)s0 * 64 + lane];
    uint u1 = yb[(size_t)s1 * 64 + lane];
    uint u2 = yb[(size_t)s2 * 64 + lane];
    uint u3 = yb[(size_t)s3 * 64 + lane];
    ax0 += __uint_as_float(u0 << 16);
    ay0 += __uint_as_float(u0 & 0xFFFF0000u);
    ax1 += __uint_as_float(u1 << 16);
    ay1 += __uint_as_float(u1 & 0xFFFF0000u);
    ax2 += __uint_as_float(u2 << 16);
    ay2 += __uint_as_float(u2 & 0xFFFF0000u);
    ax3 += __uint_as_float(u3 << 16);
    ay3 += __uint_as_float(u3 & 0xFFFF0000u);
  }
  for (; j < end; ++j) {
    int s0 = csr_src[j];
    uint u0 = yb[(size_t)s0 * 64 + lane];
    ax0 += __uint_as_float(u0 << 16);
    ay0 += __uint_as_float(u0 & 0xFFFF0000u);
  }
  float sx = (ax0 + ax1) + (ax2 + ax3);
  float sy = (ay0 + ay1) + (ay2 + ay3);

  float ni = norm_in[node];
  float2 bb = b2[lane];
  float2 o;
  o.x = fmaxf(fmaf(sx, ni, bb.x), 0.f);
  o.y = fmaxf(fmaf(sy, ni, bb.y), 0.f);
  out2[(size_t)node * 64 + lane] = o;
}

extern "C" void kernel_launch(void* const* d_in, const int* in_sizes, int n_in,
                              void* d_out, int out_size, void* d_ws, size_t ws_size,
                              hipStream_t stream) {
  const float* x  = (const float*)d_in[0];
  const int* ei   = (const int*)d_in[1];
  const float* W  = (const float*)d_in[2];
  const float* b  = (const float*)d_in[3];
  float* out      = (float*)d_out;

  const int* src = ei;
  const int* dst = ei + N_EDGES;

  // workspace layout (no memset needed: every buffer fully written before read)
  char* p = (char*)d_ws;
  uint* yb       = (uint*)p;   p += (size_t)N_NODES * DIM * sizeof(unsigned short);   // 12.8 MB
  uint* hist_src = (uint*)p;   p += (size_t)NHB * NPACK * sizeof(uint);               // 1.6 MB
  uint* hist_dst = (uint*)p;   p += (size_t)NHB * NPACK * sizeof(uint);               // 1.6 MB
  uint* P        = (uint*)p;   p += (size_t)NHB * N_NODES * sizeof(uint);             // 3.2 MB
  int* cnt_in    = (int*)p;    p += (size_t)N_NODES * sizeof(int);
  float* norm_in = (float*)p;  p += (size_t)N_NODES * sizeof(float);
  float* norm_out= (float*)p;  p += (size_t)N_NODES * sizeof(float);
  int* offsets   = (int*)p;    p += (size_t)(N_NODES + 1) * sizeof(int);
  int* partial   = (int*)p;    p += (size_t)N_NODES * sizeof(int);
  int* blockSums = (int*)p;    p += 64 * sizeof(int);
  int* csr_src   = (int*)p;    p += (size_t)N_EDGES * sizeof(int);                    // 3.2 MB

  const size_t lds_bytes = (size_t)NPACK * sizeof(uint);  // 100 KB dynamic LDS

  hist_kernel<<<NHB, 1024, lds_bytes, stream>>>(src, dst, hist_src, hist_dst);
  prefix_kernel<<<(NPACK + 255) / 256, 256, 0, stream>>>(
      hist_src, hist_dst, P, cnt_in, norm_in, norm_out);
  gemm_kernel<<<(N_NODES + 63) / 64, 256, 0, stream>>>(
      (const float4*)x, (const float4*)W, norm_out, (uint2*)yb, N_NODES);
  scan1_kernel<<<SCAN_BLOCKS, 256, 0, stream>>>(cnt_in, partial, blockSums, N_NODES);
  scan2_kernel<<<1, 64, 0, stream>>>(blockSums, SCAN_BLOCKS);
  scan3_kernel<<<SCAN_BLOCKS, 256, 0, stream>>>(partial, blockSums, offsets, N_NODES, N_EDGES);
  fill_kernel<<<NHB, 1024, lds_bytes, stream>>>(src, dst, offsets, P, csr_src);
  aggregate_kernel<<<(N_NODES + 3) / 4, 256, 0, stream>>>(
      yb, csr_src, offsets, norm_in, (const float2*)b, (float2*)out, N_NODES);
}

// Round 11
// 228.740 us; speedup vs baseline: 1.4669x; 1.4669x over previous
//
#include <hip/hip_runtime.h>

#define N_NODES 50000
#define N_EDGES 800000
#define DIM 128
#define NHB 64                          // histogram/fill blocks
#define EPB (N_EDGES / NHB)             // 12500 edges per block
#define NPACK (N_NODES / 2)             // 25000 packed dwords (2x u16 per dword)
#define SCAN_ELEMS 1024
#define SCAN_BLOCKS ((N_NODES + SCAN_ELEMS - 1) / SCAN_ELEMS)  // 49

typedef unsigned int uint;

__device__ __forceinline__ uint bf16pair(float a, float b) {
  uint ua = __float_as_uint(a); ua = (ua + 0x7FFFu + ((ua >> 16) & 1u)) >> 16;
  uint ub = __float_as_uint(b); ub = (ub + 0x7FFFu + ((ub >> 16) & 1u)) >> 16;
  return ua | (ub << 16);
}

// ---------------- per-block histograms of dst and src (LDS atomics, plain-store flush) ----------------
__global__ __launch_bounds__(1024) void hist_kernel(
    const int* __restrict__ src, const int* __restrict__ dst,
    uint* __restrict__ hist_src, uint* __restrict__ hist_dst) {
  extern __shared__ uint h[];   // NPACK dwords = 100 KB
  int b = blockIdx.x, t = threadIdx.x;
  int e0 = b * EPB;

  // dst pass
  for (int i = t; i < NPACK; i += 1024) h[i] = 0;
  __syncthreads();
  for (int i = t; i < EPB; i += 1024) {
    int d = dst[e0 + i];
    atomicAdd(&h[d >> 1], 1u << ((d & 1) << 4));
  }
  __syncthreads();
  for (int i = t; i < NPACK; i += 1024) hist_dst[b * NPACK + i] = h[i];
  __syncthreads();

  // src pass
  for (int i = t; i < NPACK; i += 1024) h[i] = 0;
  __syncthreads();
  for (int i = t; i < EPB; i += 1024) {
    int s = src[e0 + i];
    atomicAdd(&h[s >> 1], 1u << ((s & 1) << 4));
  }
  __syncthreads();
  for (int i = t; i < NPACK; i += 1024) hist_src[b * NPACK + i] = h[i];
}

// ---------------- per-node cross-block prefix (packed u16), totals, norms ----------------
__global__ __launch_bounds__(256) void prefix_kernel(
    const uint* __restrict__ hist_src, const uint* __restrict__ hist_dst,
    uint* __restrict__ Ppack, int* __restrict__ cnt_in,
    float* __restrict__ norm_in, float* __restrict__ norm_out) {
  int i = blockIdx.x * 256 + threadIdx.x;   // packed dword index: nodes 2i, 2i+1
  if (i >= NPACK) return;
  uint r0 = 0, r1 = 0;
#pragma unroll 4
  for (int b = 0; b < NHB; ++b) {
    uint v = hist_dst[b * NPACK + i];
    Ppack[b * NPACK + i] = (r0 & 0xFFFFu) | (r1 << 16);
    r0 += v & 0xFFFFu; r1 += v >> 16;
  }
  cnt_in[2 * i] = (int)r0; cnt_in[2 * i + 1] = (int)r1;
  norm_in[2 * i]     = rsqrtf(fmaxf((float)r0, 1.0f));
  norm_in[2 * i + 1] = rsqrtf(fmaxf((float)r1, 1.0f));
  uint s0 = 0, s1 = 0;
#pragma unroll 4
  for (int b = 0; b < NHB; ++b) {
    uint v = hist_src[b * NPACK + i];
    s0 += v & 0xFFFFu; s1 += v >> 16;
  }
  norm_out[2 * i]     = rsqrtf(fmaxf((float)s0, 1.0f));
  norm_out[2 * i + 1] = rsqrtf(fmaxf((float)s1, 1.0f));
}

// ---------------- scan pass 1: per-block exclusive scan of cnt_in ----------------
__global__ __launch_bounds__(256) void scan1_kernel(
    const int* __restrict__ counts, int* __restrict__ partial,
    int* __restrict__ blockSums, int n) {
  __shared__ int wsum[4];
  int t = threadIdx.x;
  int base = blockIdx.x * SCAN_ELEMS + t * 4;
  int c[4];
#pragma unroll
  for (int i = 0; i < 4; ++i) c[i] = (base + i < n) ? counts[base + i] : 0;
  int s = c[0] + c[1] + c[2] + c[3];
  int lane = t & 63, wid = t >> 6;
  int v = s;
#pragma unroll
  for (int off = 1; off < 64; off <<= 1) {
    int u = __shfl_up(v, off);
    if (lane >= off) v += u;
  }
  if (lane == 63) wsum[wid] = v;
  __syncthreads();
  if (t == 0) {
    int run = 0;
#pragma unroll
    for (int i = 0; i < 4; ++i) { int tmp = wsum[i]; wsum[i] = run; run += tmp; }
    blockSums[blockIdx.x] = run;
  }
  __syncthreads();
  int excl = wsum[wid] + v - s;
  int o0 = excl;
  int o1 = o0 + c[0];
  int o2 = o1 + c[1];
  int o3 = o2 + c[2];
  if (base + 0 < n) partial[base + 0] = o0;
  if (base + 1 < n) partial[base + 1] = o1;
  if (base + 2 < n) partial[base + 2] = o2;
  if (base + 3 < n) partial[base + 3] = o3;
}

// ---------------- scan pass 2: serial scan of 49 block sums ----------------
__global__ void scan2_kernel(int* __restrict__ blockSums, int nb) {
  if (threadIdx.x == 0 && blockIdx.x == 0) {
    int run = 0;
    for (int i = 0; i < nb; ++i) { int t = blockSums[i]; blockSums[i] = run; run += t; }
  }
}

// ---------------- scan pass 3: offsets ----------------
__global__ __launch_bounds__(256) void scan3_kernel(
    const int* __restrict__ partial, const int* __restrict__ blockSums,
    int* __restrict__ offsets, int n, int E) {
  int t = threadIdx.x;
  int bo = blockSums[blockIdx.x];
  int base = blockIdx.x * SCAN_ELEMS + t * 4;
#pragma unroll
  for (int i = 0; i < 4; ++i) {
    int idx = base + i;
    if (idx < n) offsets[idx] = partial[idx] + bo;
  }
  if (blockIdx.x == 0 && t == 0) offsets[n] = E;
}

// ---------------- bucket fill via LDS cursor (no global atomics) ----------------
__global__ __launch_bounds__(1024) void fill_kernel(
    const int* __restrict__ src, const int* __restrict__ dst,
    const int* __restrict__ offsets, const uint* __restrict__ Ppack,
    int* __restrict__ csr_src) {
  extern __shared__ uint cur[];  // NPACK dwords = 100 KB
  int b = blockIdx.x, t = threadIdx.x;
  for (int i = t; i < NPACK; i += 1024) cur[i] = 0;
  __syncthreads();
  int e0 = b * EPB;
  const uint* Pb = Ppack + b * NPACK;
  for (int i = t; i < EPB; i += 1024) {
    int d = dst[e0 + i];
    int s = src[e0 + i];
    uint sh = (uint)(d & 1) << 4;
    uint old = atomicAdd(&cur[d >> 1], 1u << sh);
    uint lpos = (old >> sh) & 0xFFFFu;
    uint pbase = (Pb[d >> 1] >> sh) & 0xFFFFu;
    csr_src[offsets[d] + (int)pbase + (int)lpos] = s;
  }
}

// ---------------- y_bf16[r] = norm_out[r] * (x[r] @ W) ----------------
// 64 rows/block; W (64KB) in LDS, A direct from global (half-wave broadcast).
__global__ __launch_bounds__(256) void gemm_kernel(
    const float4* __restrict__ x4, const float4* __restrict__ W4,
    const float* __restrict__ norm_out, uint2* __restrict__ yb2, int n) {
  __shared__ float4 Wl4[DIM * 32];  // Wl4[k*32 + c4], 64KB
  int t = threadIdx.x;
#pragma unroll
  for (int i = 0; i < 16; ++i) Wl4[t + 256 * i] = W4[t + 256 * i];
  __syncthreads();

  int col4 = t & 31;
  int rg = t >> 5;
  int row0 = blockIdx.x * 64 + rg * 8;

  float4 acc[8];
#pragma unroll
  for (int i = 0; i < 8; ++i) acc[i] = make_float4(0.f, 0.f, 0.f, 0.f);

#pragma unroll 2
  for (int kc = 0; kc < 32; ++kc) {
    float4 w0 = Wl4[(4 * kc + 0) * 32 + col4];
    float4 w1 = Wl4[(4 * kc + 1) * 32 + col4];
    float4 w2 = Wl4[(4 * kc + 2) * 32 + col4];
    float4 w3 = Wl4[(4 * kc + 3) * 32 + col4];
#pragma unroll
    for (int i = 0; i < 8; ++i) {
      int gr = row0 + i;
      int cr = gr < n ? gr : n - 1;
      float4 a = x4[(size_t)cr * 32 + kc];
      acc[i].x = fmaf(a.x, w0.x, fmaf(a.y, w1.x, fmaf(a.z, w2.x, fmaf(a.w, w3.x, acc[i].x))));
      acc[i].y = fmaf(a.x, w0.y, fmaf(a.y, w1.y, fmaf(a.z, w2.y, fmaf(a.w, w3.y, acc[i].y))));
      acc[i].z = fmaf(a.x, w0.z, fmaf(a.y, w1.z, fmaf(a.z, w2.z, fmaf(a.w, w3.z, acc[i].z))));
      acc[i].w = fmaf(a.x, w0.w, fmaf(a.y, w1.w, fmaf(a.z, w2.w, fmaf(a.w, w3.w, acc[i].w))));
    }
  }

#pragma unroll
  for (int i = 0; i < 8; ++i) {
    int gr = row0 + i;
    if (gr < n) {
      float ns = norm_out[gr];
      float4 o = acc[i];
      uint2 packed;
      packed.x = bf16pair(o.x * ns, o.y * ns);
      packed.y = bf16pair(o.z * ns, o.w * ns);
      yb2[(size_t)gr * 32 + col4] = packed;
    }
  }
}

// ---------------- out[d] = relu(norm_in[d] * sum_seg ybf16[src] + b) ----------------
__global__ __launch_bounds__(256) void aggregate_kernel(
    const uint* __restrict__ yb, const int* __restrict__ csr_src,
    const int* __restrict__ offsets, const float* __restrict__ norm_in,
    const float2* __restrict__ b2, float2* __restrict__ out2, int n) {
  int t = threadIdx.x;
  int node = blockIdx.x * 4 + (t >> 6);
  if (node >= n) return;
  int lane = t & 63;
  int beg = offsets[node], end = offsets[node + 1];

  float ax0 = 0.f, ay0 = 0.f, ax1 = 0.f, ay1 = 0.f;
  float ax2 = 0.f, ay2 = 0.f, ax3 = 0.f, ay3 = 0.f;
  int j = beg;
  for (; j + 4 <= end; j += 4) {
    int s0 = csr_src[j + 0];
    int s1 = csr_src[j + 1];
    int s2 = csr_src[j + 2];
    int s3 = csr_src[j + 3];
    uint u0 = yb[(size_t)s0 * 64 + lane];
    uint u1 = yb[(size_t)s1 * 64 + lane];
    uint u2 = yb[(size_t)s2 * 64 + lane];
    uint u3 = yb[(size_t)s3 * 64 + lane];
    ax0 += __uint_as_float(u0 << 16);
    ay0 += __uint_as_float(u0 & 0xFFFF0000u);
    ax1 += __uint_as_float(u1 << 16);
    ay1 += __uint_as_float(u1 & 0xFFFF0000u);
    ax2 += __uint_as_float(u2 << 16);
    ay2 += __uint_as_float(u2 & 0xFFFF0000u);
    ax3 += __uint_as_float(u3 << 16);
    ay3 += __uint_as_float(u3 & 0xFFFF0000u);
  }
  for (; j < end; ++j) {
    int s0 = csr_src[j];
    uint u0 = yb[(size_t)s0 * 64 + lane];
    ax0 += __uint_as_float(u0 << 16);
    ay0 += __uint_as_float(u0 & 0xFFFF0000u);
  }
  float sx = (ax0 + ax1) + (ax2 + ax3);
  float sy = (ay0 + ay1) + (ay2 + ay3);

  float ni = norm_in[node];
  float2 bb = b2[lane];
  float2 o;
  o.x = fmaxf(fmaf(sx, ni, bb.x), 0.f);
  o.y = fmaxf(fmaf(sy, ni, bb.y), 0.f);
  out2[(size_t)node * 64 + lane] = o;
}

extern "C" void kernel_launch(void* const* d_in, const int* in_sizes, int n_in,
                              void* d_out, int out_size, void* d_ws, size_t ws_size,
                              hipStream_t stream) {
  const float* x  = (const float*)d_in[0];
  const int* ei   = (const int*)d_in[1];
  const float* W  = (const float*)d_in[2];
  const float* b  = (const float*)d_in[3];
  float* out      = (float*)d_out;

  const int* src = ei;
  const int* dst = ei + N_EDGES;

  // workspace layout (no memset needed: every buffer fully written before read)
  char* p = (char*)d_ws;
  uint* yb       = (uint*)p;   p += (size_t)N_NODES * DIM * sizeof(unsigned short);   // 12.8 MB
  uint* hist_dst = (uint*)p;   p += (size_t)NHB * NPACK * sizeof(uint);               // 6.4 MB
  uint* hist_src = (uint*)p;   p += (size_t)NHB * NPACK * sizeof(uint);               // 6.4 MB
  uint* Ppack    = (uint*)p;   p += (size_t)NHB * NPACK * sizeof(uint);               // 6.4 MB
  int* cnt_in    = (int*)p;    p += (size_t)N_NODES * sizeof(int);
  float* norm_in = (float*)p;  p += (size_t)N_NODES * sizeof(float);
  float* norm_out= (float*)p;  p += (size_t)N_NODES * sizeof(float);
  int* offsets   = (int*)p;    p += (size_t)(N_NODES + 1) * sizeof(int);
  int* partial   = (int*)p;    p += (size_t)N_NODES * sizeof(int);
  int* blockSums = (int*)p;    p += 64 * sizeof(int);
  // csr_src aliases hist_src: hist_src is dead after prefix_kernel completes,
  // and fill_kernel (which writes csr_src) runs strictly after it on the stream.
  int* csr_src   = (int*)hist_src;                                                    // 3.2 MB

  const size_t lds_bytes = (size_t)NPACK * sizeof(uint);  // 100 KB dynamic LDS

  hist_kernel<<<NHB, 1024, lds_bytes, stream>>>(src, dst, hist_src, hist_dst);
  prefix_kernel<<<(NPACK + 255) / 256, 256, 0, stream>>>(
      hist_src, hist_dst, Ppack, cnt_in, norm_in, norm_out);
  gemm_kernel<<<(N_NODES + 63) / 64, 256, 0, stream>>>(
      (const float4*)x, (const float4*)W, norm_out, (uint2*)yb, N_NODES);
  scan1_kernel<<<SCAN_BLOCKS, 256, 0, stream>>>(cnt_in, partial, blockSums, N_NODES);
  scan2_kernel<<<1, 64, 0, stream>>>(blockSums, SCAN_BLOCKS);
  scan3_kernel<<<SCAN_BLOCKS, 256, 0, stream>>>(partial, blockSums, offsets, N_NODES, N_EDGES);
  fill_kernel<<<NHB, 1024, lds_bytes, stream>>>(src, dst, offsets, Ppack, csr_src);
  aggregate_kernel<<<(N_NODES + 3) / 4, 256, 0, stream>>>(
      yb, csr_src, offsets, norm_in, (const float2*)b, (float2*)out, N_NODES);
}

// Round 12
// 224.922 us; speedup vs baseline: 1.4918x; 1.0170x over previous
//
#include <hip/hip_runtime.h>

#define N_NODES 50000
#define N_EDGES 800000
#define DIM 128
#define NHB 64                          // histogram/fill blocks
#define EPB (N_EDGES / NHB)             // 12500 edges per block
#define NPACK (N_NODES / 2)             // 25000 packed dwords (2x u16 per dword)
#define SCAN_ELEMS 1024
#define SCAN_BLOCKS ((N_NODES + SCAN_ELEMS - 1) / SCAN_ELEMS)  // 49

typedef unsigned int uint;

__device__ __forceinline__ uint bf16pair(float a, float b) {
  uint ua = __float_as_uint(a); ua = (ua + 0x7FFFu + ((ua >> 16) & 1u)) >> 16;
  uint ub = __float_as_uint(b); ub = (ub + 0x7FFFu + ((ub >> 16) & 1u)) >> 16;
  return ua | (ub << 16);
}

// ---------------- per-block histograms of dst and src (LDS atomics, plain-store flush) ----------------
__global__ __launch_bounds__(1024) void hist_kernel(
    const int* __restrict__ src, const int* __restrict__ dst,
    uint* __restrict__ hist_src, uint* __restrict__ hist_dst) {
  extern __shared__ uint h[];   // NPACK dwords = 100 KB
  int b = blockIdx.x, t = threadIdx.x;
  int e0 = b * EPB;

  // dst pass
  for (int i = t; i < NPACK; i += 1024) h[i] = 0;
  __syncthreads();
  for (int i = t; i < EPB; i += 1024) {
    int d = dst[e0 + i];
    atomicAdd(&h[d >> 1], 1u << ((d & 1) << 4));
  }
  __syncthreads();
  for (int i = t; i < NPACK; i += 1024) hist_dst[b * NPACK + i] = h[i];
  __syncthreads();

  // src pass
  for (int i = t; i < NPACK; i += 1024) h[i] = 0;
  __syncthreads();
  for (int i = t; i < EPB; i += 1024) {
    int s = src[e0 + i];
    atomicAdd(&h[s >> 1], 1u << ((s & 1) << 4));
  }
  __syncthreads();
  for (int i = t; i < NPACK; i += 1024) hist_src[b * NPACK + i] = h[i];
}

// ---------------- per-node cross-block prefix (packed u16), totals, norms ----------------
__global__ __launch_bounds__(256) void prefix_kernel(
    const uint* __restrict__ hist_src, const uint* __restrict__ hist_dst,
    uint* __restrict__ Ppack, int* __restrict__ cnt_in,
    float* __restrict__ norm_in, float* __restrict__ norm_out) {
  int i = blockIdx.x * 256 + threadIdx.x;   // packed dword index: nodes 2i, 2i+1
  if (i >= NPACK) return;
  uint r0 = 0, r1 = 0;
#pragma unroll 4
  for (int b = 0; b < NHB; ++b) {
    uint v = hist_dst[b * NPACK + i];
    Ppack[b * NPACK + i] = (r0 & 0xFFFFu) | (r1 << 16);
    r0 += v & 0xFFFFu; r1 += v >> 16;
  }
  cnt_in[2 * i] = (int)r0; cnt_in[2 * i + 1] = (int)r1;
  norm_in[2 * i]     = rsqrtf(fmaxf((float)r0, 1.0f));
  norm_in[2 * i + 1] = rsqrtf(fmaxf((float)r1, 1.0f));
  uint s0 = 0, s1 = 0;
#pragma unroll 4
  for (int b = 0; b < NHB; ++b) {
    uint v = hist_src[b * NPACK + i];
    s0 += v & 0xFFFFu; s1 += v >> 16;
  }
  norm_out[2 * i]     = rsqrtf(fmaxf((float)s0, 1.0f));
  norm_out[2 * i + 1] = rsqrtf(fmaxf((float)s1, 1.0f));
}

// ---------------- scan pass 1: per-block exclusive scan of cnt_in ----------------
__global__ __launch_bounds__(256) void scan1_kernel(
    const int* __restrict__ counts, int* __restrict__ partial,
    int* __restrict__ blockSums, int n) {
  __shared__ int wsum[4];
  int t = threadIdx.x;
  int base = blockIdx.x * SCAN_ELEMS + t * 4;
  int c[4];
#pragma unroll
  for (int i = 0; i < 4; ++i) c[i] = (base + i < n) ? counts[base + i] : 0;
  int s = c[0] + c[1] + c[2] + c[3];
  int lane = t & 63, wid = t >> 6;
  int v = s;
#pragma unroll
  for (int off = 1; off < 64; off <<= 1) {
    int u = __shfl_up(v, off);
    if (lane >= off) v += u;
  }
  if (lane == 63) wsum[wid] = v;
  __syncthreads();
  if (t == 0) {
    int run = 0;
#pragma unroll
    for (int i = 0; i < 4; ++i) { int tmp = wsum[i]; wsum[i] = run; run += tmp; }
    blockSums[blockIdx.x] = run;
  }
  __syncthreads();
  int excl = wsum[wid] + v - s;
  int o0 = excl;
  int o1 = o0 + c[0];
  int o2 = o1 + c[1];
  int o3 = o2 + c[2];
  if (base + 0 < n) partial[base + 0] = o0;
  if (base + 1 < n) partial[base + 1] = o1;
  if (base + 2 < n) partial[base + 2] = o2;
  if (base + 3 < n) partial[base + 3] = o3;
}

// ---------------- scan pass 2: serial scan of 49 block sums ----------------
__global__ void scan2_kernel(int* __restrict__ blockSums, int nb) {
  if (threadIdx.x == 0 && blockIdx.x == 0) {
    int run = 0;
    for (int i = 0; i < nb; ++i) { int t = blockSums[i]; blockSums[i] = run; run += t; }
  }
}

// ---------------- scan pass 3: offsets ----------------
__global__ __launch_bounds__(256) void scan3_kernel(
    const int* __restrict__ partial, const int* __restrict__ blockSums,
    int* __restrict__ offsets, int n, int E) {
  int t = threadIdx.x;
  int bo = blockSums[blockIdx.x];
  int base = blockIdx.x * SCAN_ELEMS + t * 4;
#pragma unroll
  for (int i = 0; i < 4; ++i) {
    int idx = base + i;
    if (idx < n) offsets[idx] = partial[idx] + bo;
  }
  if (blockIdx.x == 0 && t == 0) offsets[n] = E;
}

// ---------------- bucket fill via LDS cursor (no global atomics) ----------------
__global__ __launch_bounds__(1024) void fill_kernel(
    const int* __restrict__ src, const int* __restrict__ dst,
    const int* __restrict__ offsets, const uint* __restrict__ Ppack,
    int* __restrict__ csr_src) {
  extern __shared__ uint cur[];  // NPACK dwords = 100 KB
  int b = blockIdx.x, t = threadIdx.x;
  for (int i = t; i < NPACK; i += 1024) cur[i] = 0;
  __syncthreads();
  int e0 = b * EPB;
  const uint* Pb = Ppack + b * NPACK;
  for (int i = t; i < EPB; i += 1024) {
    int d = dst[e0 + i];
    int s = src[e0 + i];
    uint sh = (uint)(d & 1) << 4;
    uint old = atomicAdd(&cur[d >> 1], 1u << sh);
    uint lpos = (old >> sh) & 0xFFFFu;
    uint pbase = (Pb[d >> 1] >> sh) & 0xFFFFu;
    csr_src[offsets[d] + (int)pbase + (int)lpos] = s;
  }
}

// ---------------- y_bf16[r] = norm_out[r] * (x[r] @ W) ----------------
// 512 threads (8 waves), 128 rows/block; W (64KB) in LDS, A direct from global
// (half-wave broadcast). LDS 64KB -> 2 blocks/CU = 4 waves/SIMD (vs 2 at 256thr).
// Thread (col4 = t&31, rowgrp = t>>5 in 0..15) computes 8 rows x 4 cols.
__global__ __launch_bounds__(512) void gemm_kernel(
    const float4* __restrict__ x4, const float4* __restrict__ W4,
    const float* __restrict__ norm_out, uint2* __restrict__ yb2, int n) {
  __shared__ float4 Wl4[DIM * 32];  // Wl4[k*32 + c4], 64KB
  int t = threadIdx.x;
#pragma unroll
  for (int i = 0; i < 8; ++i) Wl4[t + 512 * i] = W4[t + 512 * i];
  __syncthreads();

  int col4 = t & 31;
  int rg = t >> 5;                       // 0..15
  int row0 = blockIdx.x * 128 + rg * 8;  // 8 consecutive rows per thread

  float4 acc[8];
#pragma unroll
  for (int i = 0; i < 8; ++i) acc[i] = make_float4(0.f, 0.f, 0.f, 0.f);

#pragma unroll 2
  for (int kc = 0; kc < 32; ++kc) {
    float4 w0 = Wl4[(4 * kc + 0) * 32 + col4];
    float4 w1 = Wl4[(4 * kc + 1) * 32 + col4];
    float4 w2 = Wl4[(4 * kc + 2) * 32 + col4];
    float4 w3 = Wl4[(4 * kc + 3) * 32 + col4];
#pragma unroll
    for (int i = 0; i < 8; ++i) {
      int gr = row0 + i;
      int cr = gr < n ? gr : n - 1;      // clamp; OOB rows discarded at store
      float4 a = x4[(size_t)cr * 32 + kc];
      acc[i].x = fmaf(a.x, w0.x, fmaf(a.y, w1.x, fmaf(a.z, w2.x, fmaf(a.w, w3.x, acc[i].x))));
      acc[i].y = fmaf(a.x, w0.y, fmaf(a.y, w1.y, fmaf(a.z, w2.y, fmaf(a.w, w3.y, acc[i].y))));
      acc[i].z = fmaf(a.x, w0.z, fmaf(a.y, w1.z, fmaf(a.z, w2.z, fmaf(a.w, w3.z, acc[i].z))));
      acc[i].w = fmaf(a.x, w0.w, fmaf(a.y, w1.w, fmaf(a.z, w2.w, fmaf(a.w, w3.w, acc[i].w))));
    }
  }

#pragma unroll
  for (int i = 0; i < 8; ++i) {
    int gr = row0 + i;
    if (gr < n) {
      float ns = norm_out[gr];
      float4 o = acc[i];
      uint2 packed;
      packed.x = bf16pair(o.x * ns, o.y * ns);
      packed.y = bf16pair(o.z * ns, o.w * ns);
      yb2[(size_t)gr * 32 + col4] = packed;
    }
  }
}

// ---------------- out[d] = relu(norm_in[d] * sum_seg ybf16[src] + b) ----------------
__global__ __launch_bounds__(256) void aggregate_kernel(
    const uint* __restrict__ yb, const int* __restrict__ csr_src,
    const int* __restrict__ offsets, const float* __restrict__ norm_in,
    const float2* __restrict__ b2, float2* __restrict__ out2, int n) {
  int t = threadIdx.x;
  int node = blockIdx.x * 4 + (t >> 6);
  if (node >= n) return;
  int lane = t & 63;
  int beg = offsets[node], end = offsets[node + 1];

  float ax0 = 0.f, ay0 = 0.f, ax1 = 0.f, ay1 = 0.f;
  float ax2 = 0.f, ay2 = 0.f, ax3 = 0.f, ay3 = 0.f;
  int j = beg;
  for (; j + 4 <= end; j += 4) {
    int s0 = csr_src[j + 0];
    int s1 = csr_src[j + 1];
    int s2 = csr_src[j + 2];
    int s3 = csr_src[j + 3];
    uint u0 = yb[(size_t)s0 * 64 + lane];
    uint u1 = yb[(size_t)s1 * 64 + lane];
    uint u2 = yb[(size_t)s2 * 64 + lane];
    uint u3 = yb[(size_t)s3 * 64 + lane];
    ax0 += __uint_as_float(u0 << 16);
    ay0 += __uint_as_float(u0 & 0xFFFF0000u);
    ax1 += __uint_as_float(u1 << 16);
    ay1 += __uint_as_float(u1 & 0xFFFF0000u);
    ax2 += __uint_as_float(u2 << 16);
    ay2 += __uint_as_float(u2 & 0xFFFF0000u);
    ax3 += __uint_as_float(u3 << 16);
    ay3 += __uint_as_float(u3 & 0xFFFF0000u);
  }
  for (; j < end; ++j) {
    int s0 = csr_src[j];
    uint u0 = yb[(size_t)s0 * 64 + lane];
    ax0 += __uint_as_float(u0 << 16);
    ay0 += __uint_as_float(u0 & 0xFFFF0000u);
  }
  float sx = (ax0 + ax1) + (ax2 + ax3);
  float sy = (ay0 + ay1) + (ay2 + ay3);

  float ni = norm_in[node];
  float2 bb = b2[lane];
  float2 o;
  o.x = fmaxf(fmaf(sx, ni, bb.x), 0.f);
  o.y = fmaxf(fmaf(sy, ni, bb.y), 0.f);
  out2[(size_t)node * 64 + lane] = o;
}

extern "C" void kernel_launch(void* const* d_in, const int* in_sizes, int n_in,
                              void* d_out, int out_size, void* d_ws, size_t ws_size,
                              hipStream_t stream) {
  const float* x  = (const float*)d_in[0];
  const int* ei   = (const int*)d_in[1];
  const float* W  = (const float*)d_in[2];
  const float* b  = (const float*)d_in[3];
  float* out      = (float*)d_out;

  const int* src = ei;
  const int* dst = ei + N_EDGES;

  // workspace layout (no memset needed: every buffer fully written before read)
  char* p = (char*)d_ws;
  uint* yb       = (uint*)p;   p += (size_t)N_NODES * DIM * sizeof(unsigned short);   // 12.8 MB
  uint* hist_dst = (uint*)p;   p += (size_t)NHB * NPACK * sizeof(uint);               // 6.4 MB
  uint* hist_src = (uint*)p;   p += (size_t)NHB * NPACK * sizeof(uint);               // 6.4 MB
  uint* Ppack    = (uint*)p;   p += (size_t)NHB * NPACK * sizeof(uint);               // 6.4 MB
  int* cnt_in    = (int*)p;    p += (size_t)N_NODES * sizeof(int);
  float* norm_in = (float*)p;  p += (size_t)N_NODES * sizeof(float);
  float* norm_out= (float*)p;  p += (size_t)N_NODES * sizeof(float);
  int* offsets   = (int*)p;    p += (size_t)(N_NODES + 1) * sizeof(int);
  int* partial   = (int*)p;    p += (size_t)N_NODES * sizeof(int);
  int* blockSums = (int*)p;    p += 64 * sizeof(int);
  // csr_src aliases hist_src: hist_src is dead after prefix_kernel completes,
  // and fill_kernel (which writes csr_src) runs strictly after it on the stream.
  int* csr_src   = (int*)hist_src;                                                    // 3.2 MB

  const size_t lds_bytes = (size_t)NPACK * sizeof(uint);  // 100 KB dynamic LDS

  hist_kernel<<<NHB, 1024, lds_bytes, stream>>>(src, dst, hist_src, hist_dst);
  prefix_kernel<<<(NPACK + 255) / 256, 256, 0, stream>>>(
      hist_src, hist_dst, Ppack, cnt_in, norm_in, norm_out);
  gemm_kernel<<<(N_NODES + 127) / 128, 512, 0, stream>>>(
      (const float4*)x, (const float4*)W, norm_out, (uint2*)yb, N_NODES);
  scan1_kernel<<<SCAN_BLOCKS, 256, 0, stream>>>(cnt_in, partial, blockSums, N_NODES);
  scan2_kernel<<<1, 64, 0, stream>>>(blockSums, SCAN_BLOCKS);
  scan3_kernel<<<SCAN_BLOCKS, 256, 0, stream>>>(partial, blockSums, offsets, N_NODES, N_EDGES);
  fill_kernel<<<NHB, 1024, lds_bytes, stream>>>(src, dst, offsets, Ppack, csr_src);
  aggregate_kernel<<<(N_NODES + 3) / 4, 256, 0, stream>>>(
      yb, csr_src, offsets, norm_in, (const float2*)b, (float2*)out, N_NODES);
}

// Round 15
// 212.300 us; speedup vs baseline: 1.5805x; 1.0595x over previous
//
#include <hip/hip_runtime.h>

#define N_NODES 50000
#define N_EDGES 800000
#define DIM 128
#define NHB 64                          // histogram/fill blocks
#define EPB (N_EDGES / NHB)             // 12500 edges per block
#define NPACK (N_NODES / 2)             // 25000 packed dwords (2x u16 per dword)
#define SCAN_ELEMS 1024
#define SCAN_BLOCKS ((N_NODES + SCAN_ELEMS - 1) / SCAN_ELEMS)  // 49

typedef unsigned int uint;
typedef unsigned short ushort;
typedef __attribute__((ext_vector_type(8))) short short8;
typedef __attribute__((ext_vector_type(4))) float f32x4;

__device__ __forceinline__ uint bf16pair(float a, float b) {
  uint ua = __float_as_uint(a); ua = (ua + 0x7FFFu + ((ua >> 16) & 1u)) >> 16;
  uint ub = __float_as_uint(b); ub = (ub + 0x7FFFu + ((ub >> 16) & 1u)) >> 16;
  return ua | (ub << 16);
}

__device__ __forceinline__ ushort bf16one(float a) {
  uint u = __float_as_uint(a); u = (u + 0x7FFFu + ((u >> 16) & 1u)) >> 16;
  return (ushort)u;
}

// ---------------- per-block histograms of dst and src (LDS atomics, plain-store flush) ----------------
__global__ __launch_bounds__(1024) void hist_kernel(
    const int* __restrict__ src, const int* __restrict__ dst,
    uint* __restrict__ hist_src, uint* __restrict__ hist_dst) {
  extern __shared__ uint h[];   // NPACK dwords = 100 KB
  int b = blockIdx.x, t = threadIdx.x;
  int e0 = b * EPB;

  // dst pass
  for (int i = t; i < NPACK; i += 1024) h[i] = 0;
  __syncthreads();
  for (int i = t; i < EPB; i += 1024) {
    int d = dst[e0 + i];
    atomicAdd(&h[d >> 1], 1u << ((d & 1) << 4));
  }
  __syncthreads();
  for (int i = t; i < NPACK; i += 1024) hist_dst[b * NPACK + i] = h[i];
  __syncthreads();

  // src pass
  for (int i = t; i < NPACK; i += 1024) h[i] = 0;
  __syncthreads();
  for (int i = t; i < EPB; i += 1024) {
    int s = src[e0 + i];
    atomicAdd(&h[s >> 1], 1u << ((s & 1) << 4));
  }
  __syncthreads();
  for (int i = t; i < NPACK; i += 1024) hist_src[b * NPACK + i] = h[i];
}

// ---------------- per-node cross-block prefix (packed u16), totals, norms ----------------
__global__ __launch_bounds__(256) void prefix_kernel(
    const uint* __restrict__ hist_src, const uint* __restrict__ hist_dst,
    uint* __restrict__ Ppack, int* __restrict__ cnt_in,
    float* __restrict__ norm_in, float* __restrict__ norm_out) {
  int i = blockIdx.x * 256 + threadIdx.x;   // packed dword index: nodes 2i, 2i+1
  if (i >= NPACK) return;
  uint r0 = 0, r1 = 0;
#pragma unroll 4
  for (int b = 0; b < NHB; ++b) {
    uint v = hist_dst[b * NPACK + i];
    Ppack[b * NPACK + i] = (r0 & 0xFFFFu) | (r1 << 16);
    r0 += v & 0xFFFFu; r1 += v >> 16;
  }
  cnt_in[2 * i] = (int)r0; cnt_in[2 * i + 1] = (int)r1;
  norm_in[2 * i]     = rsqrtf(fmaxf((float)r0, 1.0f));
  norm_in[2 * i + 1] = rsqrtf(fmaxf((float)r1, 1.0f));
  uint s0 = 0, s1 = 0;
#pragma unroll 4
  for (int b = 0; b < NHB; ++b) {
    uint v = hist_src[b * NPACK + i];
    s0 += v & 0xFFFFu; s1 += v >> 16;
  }
  norm_out[2 * i]     = rsqrtf(fmaxf((float)s0, 1.0f));
  norm_out[2 * i + 1] = rsqrtf(fmaxf((float)s1, 1.0f));
}

// ---------------- scan pass 1: per-block exclusive scan of cnt_in ----------------
__global__ __launch_bounds__(256) void scan1_kernel(
    const int* __restrict__ counts, int* __restrict__ partial,
    int* __restrict__ blockSums, int n) {
  __shared__ int wsum[4];
  int t = threadIdx.x;
  int base = blockIdx.x * SCAN_ELEMS + t * 4;
  int c[4];
#pragma unroll
  for (int i = 0; i < 4; ++i) c[i] = (base + i < n) ? counts[base + i] : 0;
  int s = c[0] + c[1] + c[2] + c[3];
  int lane = t & 63, wid = t >> 6;
  int v = s;
#pragma unroll
  for (int off = 1; off < 64; off <<= 1) {
    int u = __shfl_up(v, off);
    if (lane >= off) v += u;
  }
  if (lane == 63) wsum[wid] = v;
  __syncthreads();
  if (t == 0) {
    int run = 0;
#pragma unroll
    for (int i = 0; i < 4; ++i) { int tmp = wsum[i]; wsum[i] = run; run += tmp; }
    blockSums[blockIdx.x] = run;
  }
  __syncthreads();
  int excl = wsum[wid] + v - s;
  int o0 = excl;
  int o1 = o0 + c[0];
  int o2 = o1 + c[1];
  int o3 = o2 + c[2];
  if (base + 0 < n) partial[base + 0] = o0;
  if (base + 1 < n) partial[base + 1] = o1;
  if (base + 2 < n) partial[base + 2] = o2;
  if (base + 3 < n) partial[base + 3] = o3;
}

// ---------------- scan pass 2: serial scan of 49 block sums ----------------
__global__ void scan2_kernel(int* __restrict__ blockSums, int nb) {
  if (threadIdx.x == 0 && blockIdx.x == 0) {
    int run = 0;
    for (int i = 0; i < nb; ++i) { int t = blockSums[i]; blockSums[i] = run; run += t; }
  }
}

// ---------------- scan pass 3: offsets ----------------
__global__ __launch_bounds__(256) void scan3_kernel(
    const int* __restrict__ partial, const int* __restrict__ blockSums,
    int* __restrict__ offsets, int n, int E) {
  int t = threadIdx.x;
  int bo = blockSums[blockIdx.x];
  int base = blockIdx.x * SCAN_ELEMS + t * 4;
#pragma unroll
  for (int i = 0; i < 4; ++i) {
    int idx = base + i;
    if (idx < n) offsets[idx] = partial[idx] + bo;
  }
  if (blockIdx.x == 0 && t == 0) offsets[n] = E;
}

// ---------------- bucket fill via LDS cursor (no global atomics) ----------------
__global__ __launch_bounds__(1024) void fill_kernel(
    const int* __restrict__ src, const int* __restrict__ dst,
    const int* __restrict__ offsets, const uint* __restrict__ Ppack,
    int* __restrict__ csr_src) {
  extern __shared__ uint cur[];  // NPACK dwords = 100 KB
  int b = blockIdx.x, t = threadIdx.x;
  for (int i = t; i < NPACK; i += 1024) cur[i] = 0;
  __syncthreads();
  int e0 = b * EPB;
  const uint* Pb = Ppack + b * NPACK;
  for (int i = t; i < EPB; i += 1024) {
    int d = dst[e0 + i];
    int s = src[e0 + i];
    uint sh = (uint)(d & 1) << 4;
    uint old = atomicAdd(&cur[d >> 1], 1u << sh);
    uint lpos = (old >> sh) & 0xFFFFu;
    uint pbase = (Pb[d >> 1] >> sh) & 0xFFFFu;
    csr_src[offsets[d] + (int)pbase + (int)lpos] = s;
  }
}

// ---------------- W (fp32 [k][n]) -> Wt bf16 [n][k] (transposed, B-fragment friendly) ----------------
__global__ __launch_bounds__(256) void wcvt_kernel(
    const float* __restrict__ W, ushort* __restrict__ wt) {
  int i = blockIdx.x * 256 + threadIdx.x;   // i = c*128 + k
  int c = i >> 7, k = i & 127;
  wt[i] = bf16one(W[k * 128 + c]);
}

// ---------------- y_bf16[r] = norm_out[r] * (x[r] @ W), via bf16 MFMA ----------------
// 256 threads = 4 waves, no LDS. Block tile: 64 rows x 128 cols; wave w owns cols
// [w*32, w*32+32). B-frags (Wt, bf16, L2-hot) held in registers for whole block.
// mfma_f32_16x16x32_bf16: A row=lane&15, k=(lane>>4)*8+j; B col=lane&15, same k;
// D col=lane&15, row=(lane>>4)*4+reg  [m89-verified layouts].
__global__ __launch_bounds__(256) void gemm_kernel(
    const float* __restrict__ x, const uint* __restrict__ wt,
    const float* __restrict__ norm_out, ushort* __restrict__ yb, int n) {
  int t = threadIdx.x;
  int wid = t >> 6, lane = t & 63;
  int lr = lane & 15;        // A-row / B-col / D-col within tile
  int lk = lane >> 4;        // k-group (k0 = lk*8); D row-group = lk*4
  int col0 = wid * 32;
  int brow = blockIdx.x * 64;

  // B fragments: bu[ct][kc] = Wt[col0+ct*16+lr][kc*32+lk*8 .. +7] (8 bf16 = uint4)
  uint4 bu[2][4];
#pragma unroll
  for (int ct = 0; ct < 2; ++ct) {
    const uint* bp = wt + (col0 + ct * 16 + lr) * 64 + lk * 4;
#pragma unroll
    for (int kc = 0; kc < 4; ++kc)
      bu[ct][kc] = *(const uint4*)(bp + kc * 16);
  }

#pragma unroll
  for (int rt = 0; rt < 4; ++rt) {
    int arow = brow + rt * 16 + lr;
    int crow = arow < n ? arow : n - 1;   // clamp; OOB rows discarded at store
    const float* ap = x + (size_t)crow * 128 + lk * 8;

    uint4 au[4];
#pragma unroll
    for (int kc = 0; kc < 4; ++kc) {
      float4 a0 = *(const float4*)(ap + kc * 32);
      float4 a1 = *(const float4*)(ap + kc * 32 + 4);
      uint4 u;
      u.x = bf16pair(a0.x, a0.y); u.y = bf16pair(a0.z, a0.w);
      u.z = bf16pair(a1.x, a1.y); u.w = bf16pair(a1.z, a1.w);
      au[kc] = u;
    }

    f32x4 acc0 = {0.f, 0.f, 0.f, 0.f};
    f32x4 acc1 = {0.f, 0.f, 0.f, 0.f};
#pragma unroll
    for (int kc = 0; kc < 4; ++kc) {
      short8 a = *(short8*)&au[kc];
      acc0 = __builtin_amdgcn_mfma_f32_16x16x32_bf16(a, *(short8*)&bu[0][kc], acc0, 0, 0, 0);
      acc1 = __builtin_amdgcn_mfma_f32_16x16x32_bf16(a, *(short8*)&bu[1][kc], acc1, 0, 0, 0);
    }

#pragma unroll
    for (int j = 0; j < 4; ++j) {
      int grow = brow + rt * 16 + lk * 4 + j;
      if (grow < n) {
        float ns = norm_out[grow];
        size_t base = (size_t)grow * 128;
        yb[base + col0 + lr]      = bf16one(acc0[j] * ns);
        yb[base + col0 + 16 + lr] = bf16one(acc1[j] * ns);
      }
    }
  }
}

// ---------------- out[d] = relu(norm_in[d] * sum_seg ybf16[src] + b) ----------------
__global__ __launch_bounds__(256) void aggregate_kernel(
    const uint* __restrict__ yb, const int* __restrict__ csr_src,
    const int* __restrict__ offsets, const float* __restrict__ norm_in,
    const float2* __restrict__ b2, float2* __restrict__ out2, int n) {
  int t = threadIdx.x;
  int node = blockIdx.x * 4 + (t >> 6);
  if (node >= n) return;
  int lane = t & 63;
  int beg = offsets[node], end = offsets[node + 1];

  float ax0 = 0.f, ay0 = 0.f, ax1 = 0.f, ay1 = 0.f;
  float ax2 = 0.f, ay2 = 0.f, ax3 = 0.f, ay3 = 0.f;
  int j = beg;
  for (; j + 4 <= end; j += 4) {
    int s0 = csr_src[j + 0];
    int s1 = csr_src[j + 1];
    int s2 = csr_src[j + 2];
    int s3 = csr_src[j + 3];
    uint u0 = yb[(size_t)s0 * 64 + lane];
    uint u1 = yb[(size_t)s1 * 64 + lane];
    uint u2 = yb[(size_t)s2 * 64 + lane];
    uint u3 = yb[(size_t)s3 * 64 + lane];
    ax0 += __uint_as_float(u0 << 16);
    ay0 += __uint_as_float(u0 & 0xFFFF0000u);
    ax1 += __uint_as_float(u1 << 16);
    ay1 += __uint_as_float(u1 & 0xFFFF0000u);
    ax2 += __uint_as_float(u2 << 16);
    ay2 += __uint_as_float(u2 & 0xFFFF0000u);
    ax3 += __uint_as_float(u3 << 16);
    ay3 += __uint_as_float(u3 & 0xFFFF0000u);
  }
  for (; j < end; ++j) {
    int s0 = csr_src[j];
    uint u0 = yb[(size_t)s0 * 64 + lane];
    ax0 += __uint_as_float(u0 << 16);
    ay0 += __uint_as_float(u0 & 0xFFFF0000u);
  }
  float sx = (ax0 + ax1) + (ax2 + ax3);
  float sy = (ay0 + ay1) + (ay2 + ay3);

  float ni = norm_in[node];
  float2 bb = b2[lane];
  float2 o;
  o.x = fmaxf(fmaf(sx, ni, bb.x), 0.f);
  o.y = fmaxf(fmaf(sy, ni, bb.y), 0.f);
  out2[(size_t)node * 64 + lane] = o;
}

extern "C" void kernel_launch(void* const* d_in, const int* in_sizes, int n_in,
                              void* d_out, int out_size, void* d_ws, size_t ws_size,
                              hipStream_t stream) {
  const float* x  = (const float*)d_in[0];
  const int* ei   = (const int*)d_in[1];
  const float* W  = (const float*)d_in[2];
  const float* b  = (const float*)d_in[3];
  float* out      = (float*)d_out;

  const int* src = ei;
  const int* dst = ei + N_EDGES;

  // workspace layout (no memset needed: every buffer fully written before read)
  char* p = (char*)d_ws;
  uint* yb       = (uint*)p;   p += (size_t)N_NODES * DIM * sizeof(ushort);           // 12.8 MB
  ushort* wt     = (ushort*)p; p += (size_t)DIM * DIM * sizeof(ushort);               // 32 KB (16B-aligned)
  uint* hist_dst = (uint*)p;   p += (size_t)NHB * NPACK * sizeof(uint);               // 6.4 MB
  uint* hist_src = (uint*)p;   p += (size_t)NHB * NPACK * sizeof(uint);               // 6.4 MB
  uint* Ppack    = (uint*)p;   p += (size_t)NHB * NPACK * sizeof(uint);               // 6.4 MB
  int* cnt_in    = (int*)p;    p += (size_t)N_NODES * sizeof(int);
  float* norm_in = (float*)p;  p += (size_t)N_NODES * sizeof(float);
  float* norm_out= (float*)p;  p += (size_t)N_NODES * sizeof(float);
  int* offsets   = (int*)p;    p += (size_t)(N_NODES + 1) * sizeof(int);
  int* partial   = (int*)p;    p += (size_t)N_NODES * sizeof(int);
  int* blockSums = (int*)p;    p += 64 * sizeof(int);
  // csr_src aliases hist_src: hist_src is dead after prefix_kernel completes,
  // and fill_kernel (which writes csr_src) runs strictly after it on the stream.
  int* csr_src   = (int*)hist_src;                                                    // 3.2 MB

  const size_t lds_bytes = (size_t)NPACK * sizeof(uint);  // 100 KB dynamic LDS

  wcvt_kernel<<<(DIM * DIM) / 256, 256, 0, stream>>>(W, wt);
  hist_kernel<<<NHB, 1024, lds_bytes, stream>>>(src, dst, hist_src, hist_dst);
  prefix_kernel<<<(NPACK + 255) / 256, 256, 0, stream>>>(
      hist_src, hist_dst, Ppack, cnt_in, norm_in, norm_out);
  gemm_kernel<<<(N_NODES + 63) / 64, 256, 0, stream>>>(
      x, (const uint*)wt, norm_out, (ushort*)yb, N_NODES);
  scan1_kernel<<<SCAN_BLOCKS, 256, 0, stream>>>(cnt_in, partial, blockSums, N_NODES);
  scan2_kernel<<<1, 64, 0, stream>>>(blockSums, SCAN_BLOCKS);
  scan3_kernel<<<SCAN_BLOCKS, 256, 0, stream>>>(partial, blockSums, offsets, N_NODES, N_EDGES);
  fill_kernel<<<NHB, 1024, lds_bytes, stream>>>(src, dst, offsets, Ppack, csr_src);
  aggregate_kernel<<<(N_NODES + 3) / 4, 256, 0, stream>>>(
      yb, csr_src, offsets, norm_in, (const float2*)b, (float2*)out, N_NODES);
}

// Round 16
// 204.538 us; speedup vs baseline: 1.6405x; 1.0380x over previous
//
#include <hip/hip_runtime.h>

#define N_NODES 50000
#define N_EDGES 800000
#define DIM 128
#define NHB 64                          // histogram/fill blocks
#define EPB (N_EDGES / NHB)             // 12500 edges per block
#define NPACK (N_NODES / 2)             // 25000 packed dwords (2x u16 per dword)
#define SCAN_ELEMS 1024
#define SCAN_BLOCKS ((N_NODES + SCAN_ELEMS - 1) / SCAN_ELEMS)  // 49
#define X8 (N_NODES * DIM / 8)          // 800000 uint4-groups of 8 bf16

typedef unsigned int uint;
typedef unsigned short ushort;
typedef __attribute__((ext_vector_type(8))) short short8;
typedef __attribute__((ext_vector_type(4))) float f32x4;

__device__ __forceinline__ uint bf16pair(float a, float b) {
  uint ua = __float_as_uint(a); ua = (ua + 0x7FFFu + ((ua >> 16) & 1u)) >> 16;
  uint ub = __float_as_uint(b); ub = (ub + 0x7FFFu + ((ub >> 16) & 1u)) >> 16;
  return ua | (ub << 16);
}

__device__ __forceinline__ ushort bf16one(float a) {
  uint u = __float_as_uint(a); u = (u + 0x7FFFu + ((u >> 16) & 1u)) >> 16;
  return (ushort)u;
}

// ---------------- fused converts: W -> Wt bf16 [n][k]; x -> xb bf16 ----------------
// blocks [0,64): wt (16384 elems exactly); blocks [64, 64+3125): x (vectorized 8/thread)
__global__ __launch_bounds__(256) void cvt_kernel(
    const float* __restrict__ W, ushort* __restrict__ wt,
    const float4* __restrict__ x4, uint4* __restrict__ xb4) {
  int b = blockIdx.x;
  if (b < 64) {
    int i = b * 256 + threadIdx.x;        // i = c*128 + k
    int c = i >> 7, k = i & 127;
    wt[i] = bf16one(W[k * 128 + c]);
  } else {
    int i = (b - 64) * 256 + threadIdx.x; // 8 floats per thread
    if (i < X8) {
      float4 a0 = x4[2 * i], a1 = x4[2 * i + 1];
      uint4 u;
      u.x = bf16pair(a0.x, a0.y); u.y = bf16pair(a0.z, a0.w);
      u.z = bf16pair(a1.x, a1.y); u.w = bf16pair(a1.z, a1.w);
      xb4[i] = u;
    }
  }
}

// ---------------- per-block histograms of dst and src (LDS atomics, plain-store flush) ----------------
__global__ __launch_bounds__(1024) void hist_kernel(
    const int* __restrict__ src, const int* __restrict__ dst,
    uint* __restrict__ hist_src, uint* __restrict__ hist_dst) {
  extern __shared__ uint h[];   // NPACK dwords = 100 KB
  int b = blockIdx.x, t = threadIdx.x;
  int e0 = b * EPB;

  // dst pass
  for (int i = t; i < NPACK; i += 1024) h[i] = 0;
  __syncthreads();
  for (int i = t; i < EPB; i += 1024) {
    int d = dst[e0 + i];
    atomicAdd(&h[d >> 1], 1u << ((d & 1) << 4));
  }
  __syncthreads();
  for (int i = t; i < NPACK; i += 1024) hist_dst[b * NPACK + i] = h[i];
  __syncthreads();

  // src pass
  for (int i = t; i < NPACK; i += 1024) h[i] = 0;
  __syncthreads();
  for (int i = t; i < EPB; i += 1024) {
    int s = src[e0 + i];
    atomicAdd(&h[s >> 1], 1u << ((s & 1) << 4));
  }
  __syncthreads();
  for (int i = t; i < NPACK; i += 1024) hist_src[b * NPACK + i] = h[i];
}

// ---------------- per-node cross-block prefix (packed u16), totals, norms ----------------
__global__ __launch_bounds__(256) void prefix_kernel(
    const uint* __restrict__ hist_src, const uint* __restrict__ hist_dst,
    uint* __restrict__ Ppack, int* __restrict__ cnt_in,
    float* __restrict__ norm_in, float* __restrict__ norm_out) {
  int i = blockIdx.x * 256 + threadIdx.x;   // packed dword index: nodes 2i, 2i+1
  if (i >= NPACK) return;
  uint r0 = 0, r1 = 0;
#pragma unroll 4
  for (int b = 0; b < NHB; ++b) {
    uint v = hist_dst[b * NPACK + i];
    Ppack[b * NPACK + i] = (r0 & 0xFFFFu) | (r1 << 16);
    r0 += v & 0xFFFFu; r1 += v >> 16;
  }
  cnt_in[2 * i] = (int)r0; cnt_in[2 * i + 1] = (int)r1;
  norm_in[2 * i]     = rsqrtf(fmaxf((float)r0, 1.0f));
  norm_in[2 * i + 1] = rsqrtf(fmaxf((float)r1, 1.0f));
  uint s0 = 0, s1 = 0;
#pragma unroll 4
  for (int b = 0; b < NHB; ++b) {
    uint v = hist_src[b * NPACK + i];
    s0 += v & 0xFFFFu; s1 += v >> 16;
  }
  norm_out[2 * i]     = rsqrtf(fmaxf((float)s0, 1.0f));
  norm_out[2 * i + 1] = rsqrtf(fmaxf((float)s1, 1.0f));
}

// ---------------- scan pass 1: per-block exclusive scan of cnt_in ----------------
__global__ __launch_bounds__(256) void scan1_kernel(
    const int* __restrict__ counts, int* __restrict__ partial,
    int* __restrict__ blockSums, int n) {
  __shared__ int wsum[4];
  int t = threadIdx.x;
  int base = blockIdx.x * SCAN_ELEMS + t * 4;
  int c[4];
#pragma unroll
  for (int i = 0; i < 4; ++i) c[i] = (base + i < n) ? counts[base + i] : 0;
  int s = c[0] + c[1] + c[2] + c[3];
  int lane = t & 63, wid = t >> 6;
  int v = s;
#pragma unroll
  for (int off = 1; off < 64; off <<= 1) {
    int u = __shfl_up(v, off);
    if (lane >= off) v += u;
  }
  if (lane == 63) wsum[wid] = v;
  __syncthreads();
  if (t == 0) {
    int run = 0;
#pragma unroll
    for (int i = 0; i < 4; ++i) { int tmp = wsum[i]; wsum[i] = run; run += tmp; }
    blockSums[blockIdx.x] = run;
  }
  __syncthreads();
  int excl = wsum[wid] + v - s;
  int o0 = excl;
  int o1 = o0 + c[0];
  int o2 = o1 + c[1];
  int o3 = o2 + c[2];
  if (base + 0 < n) partial[base + 0] = o0;
  if (base + 1 < n) partial[base + 1] = o1;
  if (base + 2 < n) partial[base + 2] = o2;
  if (base + 3 < n) partial[base + 3] = o3;
}

// ---------------- scan pass 2: serial scan of 49 block sums ----------------
__global__ void scan2_kernel(int* __restrict__ blockSums, int nb) {
  if (threadIdx.x == 0 && blockIdx.x == 0) {
    int run = 0;
    for (int i = 0; i < nb; ++i) { int t = blockSums[i]; blockSums[i] = run; run += t; }
  }
}

// ---------------- scan pass 3: offsets ----------------
__global__ __launch_bounds__(256) void scan3_kernel(
    const int* __restrict__ partial, const int* __restrict__ blockSums,
    int* __restrict__ offsets, int n, int E) {
  int t = threadIdx.x;
  int bo = blockSums[blockIdx.x];
  int base = blockIdx.x * SCAN_ELEMS + t * 4;
#pragma unroll
  for (int i = 0; i < 4; ++i) {
    int idx = base + i;
    if (idx < n) offsets[idx] = partial[idx] + bo;
  }
  if (blockIdx.x == 0 && t == 0) offsets[n] = E;
}

// ---------------- bucket fill via LDS cursor (no global atomics) ----------------
__global__ __launch_bounds__(1024) void fill_kernel(
    const int* __restrict__ src, const int* __restrict__ dst,
    const int* __restrict__ offsets, const uint* __restrict__ Ppack,
    int* __restrict__ csr_src) {
  extern __shared__ uint cur[];  // NPACK dwords = 100 KB
  int b = blockIdx.x, t = threadIdx.x;
  for (int i = t; i < NPACK; i += 1024) cur[i] = 0;
  __syncthreads();
  int e0 = b * EPB;
  const uint* Pb = Ppack + b * NPACK;
  for (int i = t; i < EPB; i += 1024) {
    int d = dst[e0 + i];
    int s = src[e0 + i];
    uint sh = (uint)(d & 1) << 4;
    uint old = atomicAdd(&cur[d >> 1], 1u << sh);
    uint lpos = (old >> sh) & 0xFFFFu;
    uint pbase = (Pb[d >> 1] >> sh) & 0xFFFFu;
    csr_src[offsets[d] + (int)pbase + (int)lpos] = s;
  }
}

// ---------------- y_bf16[r] = norm_out[r] * (xb[r] @ Wt^T), via bf16 MFMA ----------------
// 256 threads = 4 waves, no LDS. Block tile: 64 rows x 128 cols; wave w owns cols
// [w*32, w*32+32). A now pre-converted bf16 (xb): one uint4 load per fragment.
// mfma_f32_16x16x32_bf16: A row=lane&15, k=(lane>>4)*8+j; B col=lane&15, same k;
// D col=lane&15, row=(lane>>4)*4+reg  [m89-verified layouts].
__global__ __launch_bounds__(256) void gemm_kernel(
    const uint4* __restrict__ xb4, const uint* __restrict__ wt,
    const float* __restrict__ norm_out, ushort* __restrict__ yb, int n) {
  int t = threadIdx.x;
  int wid = t >> 6, lane = t & 63;
  int lr = lane & 15;        // A-row / B-col / D-col within tile
  int lk = lane >> 4;        // k-group (k0 = lk*8); D row-group = lk*4
  int col0 = wid * 32;
  int brow = blockIdx.x * 64;

  // B fragments: bu[ct][kc] = Wt[col0+ct*16+lr][kc*32+lk*8 .. +7] (8 bf16 = uint4)
  uint4 bu[2][4];
#pragma unroll
  for (int ct = 0; ct < 2; ++ct) {
    const uint* bp = wt + (col0 + ct * 16 + lr) * 64 + lk * 4;
#pragma unroll
    for (int kc = 0; kc < 4; ++kc)
      bu[ct][kc] = *(const uint4*)(bp + kc * 16);
  }

#pragma unroll
  for (int rt = 0; rt < 4; ++rt) {
    int arow = brow + rt * 16 + lr;
    int crow = arow < n ? arow : n - 1;   // clamp; OOB rows discarded at store
    const uint4* ap = xb4 + (size_t)crow * 16 + lk;  // row = 16 uint4; frag kc at +kc*4

    uint4 au[4];
#pragma unroll
    for (int kc = 0; kc < 4; ++kc) au[kc] = ap[kc * 4];

    f32x4 acc0 = {0.f, 0.f, 0.f, 0.f};
    f32x4 acc1 = {0.f, 0.f, 0.f, 0.f};
#pragma unroll
    for (int kc = 0; kc < 4; ++kc) {
      short8 a = *(short8*)&au[kc];
      acc0 = __builtin_amdgcn_mfma_f32_16x16x32_bf16(a, *(short8*)&bu[0][kc], acc0, 0, 0, 0);
      acc1 = __builtin_amdgcn_mfma_f32_16x16x32_bf16(a, *(short8*)&bu[1][kc], acc1, 0, 0, 0);
    }

#pragma unroll
    for (int j = 0; j < 4; ++j) {
      int grow = brow + rt * 16 + lk * 4 + j;
      if (grow < n) {
        float ns = norm_out[grow];
        size_t base = (size_t)grow * 128;
        yb[base + col0 + lr]      = bf16one(acc0[j] * ns);
        yb[base + col0 + 16 + lr] = bf16one(acc1[j] * ns);
      }
    }
  }
}

// ---------------- out[d] = relu(norm_in[d] * sum_seg ybf16[src] + b) ----------------
// one wave per node; lane owns 2 features; 8-deep MLP unroll
__global__ __launch_bounds__(256) void aggregate_kernel(
    const uint* __restrict__ yb, const int* __restrict__ csr_src,
    const int* __restrict__ offsets, const float* __restrict__ norm_in,
    const float2* __restrict__ b2, float2* __restrict__ out2, int n) {
  int t = threadIdx.x;
  int node = blockIdx.x * 4 + (t >> 6);
  if (node >= n) return;
  int lane = t & 63;
  int beg = offsets[node], end = offsets[node + 1];

  float ax0 = 0.f, ay0 = 0.f, ax1 = 0.f, ay1 = 0.f;
  float ax2 = 0.f, ay2 = 0.f, ax3 = 0.f, ay3 = 0.f;
  float ax4 = 0.f, ay4 = 0.f, ax5 = 0.f, ay5 = 0.f;
  float ax6 = 0.f, ay6 = 0.f, ax7 = 0.f, ay7 = 0.f;
  int j = beg;
  for (; j + 8 <= end; j += 8) {
    int s0 = csr_src[j + 0];
    int s1 = csr_src[j + 1];
    int s2 = csr_src[j + 2];
    int s3 = csr_src[j + 3];
    int s4 = csr_src[j + 4];
    int s5 = csr_src[j + 5];
    int s6 = csr_src[j + 6];
    int s7 = csr_src[j + 7];
    uint u0 = yb[(size_t)s0 * 64 + lane];
    uint u1 = yb[(size_t)s1 * 64 + lane];
    uint u2 = yb[(size_t)s2 * 64 + lane];
    uint u3 = yb[(size_t)s3 * 64 + lane];
    uint u4 = yb[(size_t)s4 * 64 + lane];
    uint u5 = yb[(size_t)s5 * 64 + lane];
    uint u6 = yb[(size_t)s6 * 64 + lane];
    uint u7 = yb[(size_t)s7 * 64 + lane];
    ax0 += __uint_as_float(u0 << 16); ay0 += __uint_as_float(u0 & 0xFFFF0000u);
    ax1 += __uint_as_float(u1 << 16); ay1 += __uint_as_float(u1 & 0xFFFF0000u);
    ax2 += __uint_as_float(u2 << 16); ay2 += __uint_as_float(u2 & 0xFFFF0000u);
    ax3 += __uint_as_float(u3 << 16); ay3 += __uint_as_float(u3 & 0xFFFF0000u);
    ax4 += __uint_as_float(u4 << 16); ay4 += __uint_as_float(u4 & 0xFFFF0000u);
    ax5 += __uint_as_float(u5 << 16); ay5 += __uint_as_float(u5 & 0xFFFF0000u);
    ax6 += __uint_as_float(u6 << 16); ay6 += __uint_as_float(u6 & 0xFFFF0000u);
    ax7 += __uint_as_float(u7 << 16); ay7 += __uint_as_float(u7 & 0xFFFF0000u);
  }
  for (; j + 4 <= end; j += 4) {
    int s0 = csr_src[j + 0];
    int s1 = csr_src[j + 1];
    int s2 = csr_src[j + 2];
    int s3 = csr_src[j + 3];
    uint u0 = yb[(size_t)s0 * 64 + lane];
    uint u1 = yb[(size_t)s1 * 64 + lane];
    uint u2 = yb[(size_t)s2 * 64 + lane];
    uint u3 = yb[(size_t)s3 * 64 + lane];
    ax0 += __uint_as_float(u0 << 16); ay0 += __uint_as_float(u0 & 0xFFFF0000u);
    ax1 += __uint_as_float(u1 << 16); ay1 += __uint_as_float(u1 & 0xFFFF0000u);
    ax2 += __uint_as_float(u2 << 16); ay2 += __uint_as_float(u2 & 0xFFFF0000u);
    ax3 += __uint_as_float(u3 << 16); ay3 += __uint_as_float(u3 & 0xFFFF0000u);
  }
  for (; j < end; ++j) {
    int s0 = csr_src[j];
    uint u0 = yb[(size_t)s0 * 64 + lane];
    ax0 += __uint_as_float(u0 << 16); ay0 += __uint_as_float(u0 & 0xFFFF0000u);
  }
  float sx = ((ax0 + ax1) + (ax2 + ax3)) + ((ax4 + ax5) + (ax6 + ax7));
  float sy = ((ay0 + ay1) + (ay2 + ay3)) + ((ay4 + ay5) + (ay6 + ay7));

  float ni = norm_in[node];
  float2 bb = b2[lane];
  float2 o;
  o.x = fmaxf(fmaf(sx, ni, bb.x), 0.f);
  o.y = fmaxf(fmaf(sy, ni, bb.y), 0.f);
  out2[(size_t)node * 64 + lane] = o;
}

extern "C" void kernel_launch(void* const* d_in, const int* in_sizes, int n_in,
                              void* d_out, int out_size, void* d_ws, size_t ws_size,
                              hipStream_t stream) {
  const float* x  = (const float*)d_in[0];
  const int* ei   = (const int*)d_in[1];
  const float* W  = (const float*)d_in[2];
  const float* b  = (const float*)d_in[3];
  float* out      = (float*)d_out;

  const int* src = ei;
  const int* dst = ei + N_EDGES;

  // workspace layout (no memset needed: every buffer fully written before read)
  char* p = (char*)d_ws;
  uint* yb       = (uint*)p;   p += (size_t)N_NODES * DIM * sizeof(ushort);           // 12.8 MB
  ushort* wt     = (ushort*)p; p += (size_t)DIM * DIM * sizeof(ushort);               // 32 KB
  uint4* xb4     = (uint4*)p;  p += (size_t)N_NODES * DIM * sizeof(ushort);           // 12.8 MB bf16 x
  uint* hist_dst = (uint*)p;   p += (size_t)NHB * NPACK * sizeof(uint);               // 6.4 MB
  uint* hist_src = (uint*)p;   p += (size_t)NHB * NPACK * sizeof(uint);               // 6.4 MB
  uint* Ppack    = (uint*)p;   p += (size_t)NHB * NPACK * sizeof(uint);               // 6.4 MB
  int* cnt_in    = (int*)p;    p += (size_t)N_NODES * sizeof(int);
  float* norm_in = (float*)p;  p += (size_t)N_NODES * sizeof(float);
  float* norm_out= (float*)p;  p += (size_t)N_NODES * sizeof(float);
  int* offsets   = (int*)p;    p += (size_t)(N_NODES + 1) * sizeof(int);
  int* partial   = (int*)p;    p += (size_t)N_NODES * sizeof(int);
  int* blockSums = (int*)p;    p += 64 * sizeof(int);
  // csr_src aliases hist_src: hist_src is dead after prefix_kernel completes,
  // and fill_kernel (which writes csr_src) runs strictly after it on the stream.
  int* csr_src   = (int*)hist_src;                                                    // 3.2 MB

  const size_t lds_bytes = (size_t)NPACK * sizeof(uint);  // 100 KB dynamic LDS

  cvt_kernel<<<64 + (X8 + 255) / 256, 256, 0, stream>>>(W, wt, (const float4*)x, xb4);
  hist_kernel<<<NHB, 1024, lds_bytes, stream>>>(src, dst, hist_src, hist_dst);
  prefix_kernel<<<(NPACK + 255) / 256, 256, 0, stream>>>(
      hist_src, hist_dst, Ppack, cnt_in, norm_in, norm_out);
  gemm_kernel<<<(N_NODES + 63) / 64, 256, 0, stream>>>(
      xb4, (const uint*)wt, norm_out, (ushort*)yb, N_NODES);
  scan1_kernel<<<SCAN_BLOCKS, 256, 0, stream>>>(cnt_in, partial, blockSums, N_NODES);
  scan2_kernel<<<1, 64, 0, stream>>>(blockSums, SCAN_BLOCKS);
  scan3_kernel<<<SCAN_BLOCKS, 256, 0, stream>>>(partial, blockSums, offsets, N_NODES, N_EDGES);
  fill_kernel<<<NHB, 1024, lds_bytes, stream>>>(src, dst, offsets, Ppack, csr_src);
  aggregate_kernel<<<(N_NODES + 3) / 4, 256, 0, stream>>>(
      yb, csr_src, offsets, norm_in, (const float2*)b, (float2*)out, N_NODES);
}